// Round 1
// baseline (499.495 us; speedup 1.0000x reference)
//
#include <hip/hip_runtime.h>
#include <hip/hip_bf16.h>

#define D_MODEL 512
#define D_STATE 32
#define BATCH 8
#define SEQ 4096
#define MROWS (BATCH * SEQ)

typedef __bf16 bf16;
typedef __bf16 bf16x4 __attribute__((ext_vector_type(4)));
typedef __bf16 bf16x8 __attribute__((ext_vector_type(8)));
typedef float f32x4 __attribute__((ext_vector_type(4)));

// ---------------- K1: dt, inv(I-0.5dt A) (lower-tri), A_bar, B_bar ----------------
__global__ void k_precompute(const float* __restrict__ A, const float* __restrict__ B,
                             const float* __restrict__ log_dt,
                             float* __restrict__ A_bar, float* __restrict__ B_bar) {
  __shared__ float sM[32][32];
  __shared__ float sX[32][32];
  __shared__ float red[256];
  __shared__ float sdt;
  const int t = threadIdx.x;
  float p = 0.f;
  for (int i = t; i < D_MODEL; i += 256) {
    float v = __expf(log_dt[i]);
    v = fminf(fmaxf(v, 1e-4f), 1.0f);
    p += v;
  }
  red[t] = p;
  __syncthreads();
  for (int s = 128; s > 0; s >>= 1) {
    if (t < s) red[t] += red[t + s];
    __syncthreads();
  }
  if (t == 0) sdt = red[0] * (1.0f / D_MODEL);
  __syncthreads();
  const float dt = sdt;
  for (int i = t; i < 1024; i += 256) {
    int r = i >> 5, c = i & 31;
    sM[r][c] = (r == c ? 1.f : 0.f) - 0.5f * dt * A[i];
  }
  __syncthreads();
  // X = M^{-1} via forward substitution (M is lower triangular, diag >= 1).
  if (t < 32) {
    const int j = t;
    float xcol[32];
#pragma unroll
    for (int i = 0; i < 32; i++) {
      float sacc = 0.f;
#pragma unroll
      for (int k = 0; k < 32; k++) {
        if (k < i) sacc -= sM[i][k] * xcol[k];
      }
      float num = (i == j ? 1.f : 0.f) + sacc;
      xcol[i] = (i >= j) ? num / sM[i][i] : 0.f;
    }
    for (int i = 0; i < 32; i++) sX[i][j] = xcol[i];
  }
  __syncthreads();
  // A_bar = (I + 0.5dt A) @ X
  for (int i = t; i < 1024; i += 256) {
    int r = i >> 5, c = i & 31;
    float s = 0.f;
    for (int k = 0; k < 32; k++) {
      float p2 = (r == k ? 1.f : 0.f) + 0.5f * dt * A[r * 32 + k];
      s += p2 * sX[k][c];
    }
    A_bar[i] = s;
  }
  // B_bar = dt * X @ B   (stored [n][d])
  for (int i = t; i < D_STATE * D_MODEL; i += 256) {
    int n = i >> 9, d = i & 511;
    float s = 0.f;
    for (int k = 0; k < 32; k++) s += sX[n][k] * B[k * D_MODEL + d];
    B_bar[i] = dt * s;
  }
}

// ---------------- K1c/d: CW = W@C (bf16, [e][n]), WD = W*D (bf16, [e][d]) ----------------
__global__ void k_weights(const float* __restrict__ C, const float* __restrict__ D,
                          const float* __restrict__ W,
                          bf16* __restrict__ CW, bf16* __restrict__ WD) {
  const int b = blockIdx.x, t = threadIdx.x;
  if (b < 64) {
    const int idx = b * 256 + t;  // 0..16383
    const int e = idx >> 5, n = idx & 31;
    float s = 0.f;
    for (int d = 0; d < D_MODEL; d++) s += W[e * D_MODEL + d] * C[d * D_STATE + n];
    CW[idx] = (bf16)s;
  } else {
    for (int i = (b - 64) * 256 + t; i < D_MODEL * D_MODEL; i += 64 * 256) {
      WD[i] = (bf16)(W[i] * D[i & 511]);
    }
  }
}

// ---------------- K2: uB = x @ B_bar^T; also emit x as bf16 ----------------
__global__ __launch_bounds__(256) void k_ub(const float* __restrict__ x,
                                            const float* __restrict__ B_bar,
                                            float* __restrict__ uB,
                                            bf16* __restrict__ xb) {
  __shared__ float xs[16 * 512];
  const int t = threadIdx.x;
  const long rb = (long)blockIdx.x * 16;
  const float* src = x + rb * D_MODEL;
  bf16* xdst = xb + rb * D_MODEL;
#pragma unroll
  for (int i = 0; i < 8; i++) {
    const int idx = i * 1024 + t * 4;
    const f32x4 v = *(const f32x4*)(src + idx);
    *(f32x4*)(xs + idx) = v;
    bf16x4 h;
    h[0] = (bf16)v[0]; h[1] = (bf16)v[1]; h[2] = (bf16)v[2]; h[3] = (bf16)v[3];
    *(bf16x4*)(xdst + idx) = h;
  }
  __syncthreads();
  const int n = t & 31, rr = t >> 5;  // rr in 0..7 -> rows rr and rr+8
  float acc0 = 0.f, acc1 = 0.f;
  const float* bp = B_bar + n * D_MODEL;
  for (int d = 0; d < D_MODEL; d += 4) {
    const f32x4 b4 = *(const f32x4*)(bp + d);
    const f32x4 xa = *(const f32x4*)(xs + rr * 512 + d);
    const f32x4 xc = *(const f32x4*)(xs + (rr + 8) * 512 + d);
#pragma unroll
    for (int q = 0; q < 4; q++) {
      acc0 = fmaf(xa[q], b4[q], acc0);
      acc1 = fmaf(xc[q], b4[q], acc1);
    }
  }
  uB[(rb + rr) * D_STATE + n] = acc0;
  uB[(rb + rr + 8) * D_STATE + n] = acc1;
}

// ---------------- K3: chunked tanh scan with burn-in ----------------
#define CHUNK 256
#define NCHUNK (SEQ / CHUNK)  // 16
#define BURN 512
__global__ __launch_bounds__(64) void k_scan(const float* __restrict__ uB,
                                             const float* __restrict__ A_bar,
                                             bf16* __restrict__ S,
                                             float* __restrict__ fs_out) {
  const int b = blockIdx.x >> 4;
  const int c = blockIdx.x & 15;
  const int lane = threadIdx.x & 63;
  const int n = lane & 31;
  float a[32];
#pragma unroll
  for (int k = 0; k < 32; k += 4) {
    const f32x4 v = *(const f32x4*)(A_bar + n * 32 + k);
    a[k] = v[0]; a[k + 1] = v[1]; a[k + 2] = v[2]; a[k + 3] = v[3];
  }
  const int cs = c * CHUNK;
  const int ce = cs + CHUNK;
  int tb = cs - BURN;
  if (tb < 0) tb = 0;
  const float* ub = uB + (long)b * SEQ * D_STATE + n;
  bf16* sp = S + ((long)b * SEQ + cs) * D_STATE + n;
  float s = 0.f;
  float ubuf[8], unext[8];
#pragma unroll
  for (int i = 0; i < 8; i++) ubuf[i] = ub[(long)(tb + i) * D_STATE];
  for (int tg = tb; tg < ce; tg += 8) {
    const int tn = tg + 8;
#pragma unroll
    for (int i = 0; i < 8; i++) unext[i] = (tn < ce) ? ub[(long)(tn + i) * D_STATE] : 0.f;
#pragma unroll
    for (int i = 0; i < 8; i++) {
      const int t = tg + i;
      float acc0 = ubuf[i], acc1 = 0.f, acc2 = 0.f, acc3 = 0.f;
#pragma unroll
      for (int k = 0; k < 32; k += 4) {
        acc0 = fmaf(a[k],     __shfl(s, k,     32), acc0);
        acc1 = fmaf(a[k + 1], __shfl(s, k + 1, 32), acc1);
        acc2 = fmaf(a[k + 2], __shfl(s, k + 2, 32), acc2);
        acc3 = fmaf(a[k + 3], __shfl(s, k + 3, 32), acc3);
      }
      const float z = (acc0 + acc1) + (acc2 + acc3);
      const float e = __expf(2.f * z);
      s = 1.f - 2.f / (e + 1.f);
      if (lane < 32 && t >= cs) sp[(long)(t - cs) * D_STATE] = (bf16)s;
    }
#pragma unroll
    for (int i = 0; i < 8; i++) ubuf[i] = unext[i];
  }
  if (ce == SEQ && lane < 32) fs_out[b * D_STATE + n] = s;
}

// ---------------- K5: out = S@CW^T + xb@WD^T + b  (bf16 MFMA, 128x128 tile) ----------------
__device__ __forceinline__ void stage_tile(const void* gbase, long row0, long rowStrideB,
                                           int kByte, void* lds, int w, int lane) {
#pragma unroll
  for (int j = 0; j < 2; j++) {
    const int base_off = (w << 11) + (j << 10);
    const int boff = base_off + (lane << 4);
    const int r = boff >> 6;   // 64B per tile row (32 bf16)
    const int cb = boff & 63;
    const char* src = (const char*)gbase + (row0 + r) * rowStrideB + kByte + cb;
    __builtin_amdgcn_global_load_lds(
        (const __attribute__((address_space(1))) void*)src,
        (__attribute__((address_space(3))) void*)((char*)lds + base_off), 16, 0, 0);
  }
}

__global__ __launch_bounds__(256) void k_out(const bf16* __restrict__ xb,
                                             const bf16* __restrict__ WD,
                                             const bf16* __restrict__ Sb,
                                             const bf16* __restrict__ CW,
                                             const float* __restrict__ bias,
                                             float* __restrict__ out) {
  __shared__ bf16 As[128 * 32];
  __shared__ bf16 Bs[128 * 32];
  const int tid = threadIdx.x;
  const int w = tid >> 6, lane = tid & 63;
  const int bm = blockIdx.x >> 2, bn = blockIdx.x & 3;
  const long rowbase = (long)bm * 128;
  const long colbase = (long)bn * 128;
  const int wr = w >> 1, wc = w & 1;
  const int l15 = lane & 15, kg = lane >> 4;

  f32x4 acc[4][4];
#pragma unroll
  for (int m = 0; m < 4; m++)
#pragma unroll
    for (int n = 0; n < 4; n++) acc[m][n] = (f32x4)(0.0f);

  const int aoff = (wr * 64 + l15) * 32 + kg * 8;
  const int boff = (wc * 64 + l15) * 32 + kg * 8;

  for (int kt = 0; kt < 17; kt++) {
    if (kt < 16) {
      stage_tile(xb, rowbase, 1024, kt * 64, As, w, lane);
      stage_tile(WD, colbase, 1024, kt * 64, Bs, w, lane);
    } else {
      stage_tile(Sb, rowbase, 64, 0, As, w, lane);
      stage_tile(CW, colbase, 64, 0, Bs, w, lane);
    }
    __syncthreads();
    bf16x8 af[4], bfr[4];
#pragma unroll
    for (int m = 0; m < 4; m++) af[m] = *(const bf16x8*)&As[aoff + m * 16 * 32];
#pragma unroll
    for (int n = 0; n < 4; n++) bfr[n] = *(const bf16x8*)&Bs[boff + n * 16 * 32];
#pragma unroll
    for (int m = 0; m < 4; m++)
#pragma unroll
      for (int n = 0; n < 4; n++)
        acc[m][n] = __builtin_amdgcn_mfma_f32_16x16x32_bf16(af[m], bfr[n], acc[m][n], 0, 0, 0);
    __syncthreads();
  }
#pragma unroll
  for (int n = 0; n < 4; n++) {
    const int e = (int)colbase + wc * 64 + n * 16 + l15;
    const float bv = bias[e];
#pragma unroll
    for (int m = 0; m < 4; m++) {
      const long r0 = rowbase + wr * 64 + m * 16 + kg * 4;
      const f32x4 v = acc[m][n];
#pragma unroll
      for (int jj = 0; jj < 4; jj++) out[(r0 + jj) * (long)D_MODEL + e] = v[jj] + bv;
    }
  }
}

extern "C" void kernel_launch(void* const* d_in, const int* in_sizes, int n_in,
                              void* d_out, int out_size, void* d_ws, size_t ws_size,
                              hipStream_t stream) {
  const float* x      = (const float*)d_in[0];
  const float* A      = (const float*)d_in[1];
  const float* B      = (const float*)d_in[2];
  const float* C      = (const float*)d_in[3];
  const float* D      = (const float*)d_in[4];
  const float* log_dt = (const float*)d_in[5];
  const float* W      = (const float*)d_in[6];
  const float* b_out  = (const float*)d_in[7];
  float* out = (float*)d_out;
  float* fs  = out + (long)MROWS * D_MODEL;  // final_state (8x32) after y

  char* ws = (char*)d_ws;
  float* A_bar = (float*)(ws + 0);                    // 4 KB
  float* B_bar = (float*)(ws + (4L << 10));           // 64 KB
  bf16*  CW    = (bf16*)(ws + (68L << 10));           // 32 KB
  bf16*  WD    = (bf16*)(ws + (100L << 10));          // 512 KB
  bf16*  Sb    = (bf16*)(ws + (612L << 10));          // 2 MB
  float* uB    = (float*)(ws + (2660L << 10));        // 4 MB
  bf16*  xb    = (bf16*)(ws + (6756L << 10));         // 32 MB   (total ~38.6 MB)

  k_precompute<<<dim3(1), dim3(256), 0, stream>>>(A, B, log_dt, A_bar, B_bar);
  k_weights<<<dim3(128), dim3(256), 0, stream>>>(C, D, W, CW, WD);
  k_ub<<<dim3(MROWS / 16), dim3(256), 0, stream>>>(x, B_bar, uB, xb);
  k_scan<<<dim3(BATCH * NCHUNK), dim3(64), 0, stream>>>(uB, A_bar, Sb, fs);
  k_out<<<dim3((MROWS / 128) * (D_MODEL / 128)), dim3(256), 0, stream>>>(xb, WD, Sb, CW, b_out, out);
}

// Round 2
// 246.129 us; speedup vs baseline: 2.0294x; 2.0294x over previous
//
#include <hip/hip_runtime.h>
#include <hip/hip_bf16.h>

#define D_MODEL 512
#define D_STATE 32
#define BATCH 8
#define SEQ 4096
#define MROWS (BATCH * SEQ)

typedef __bf16 bf16;
typedef __bf16 bf16x4 __attribute__((ext_vector_type(4)));
typedef __bf16 bf16x8 __attribute__((ext_vector_type(8)));
typedef float f32x4 __attribute__((ext_vector_type(4)));

// ---------------- K1: dt, inv(I-0.5dt A) (lower-tri), A_bar, B_bar ----------------
__global__ void k_precompute(const float* __restrict__ A, const float* __restrict__ B,
                             const float* __restrict__ log_dt,
                             float* __restrict__ A_bar, float* __restrict__ B_bar) {
  __shared__ float sM[32][32];
  __shared__ float sX[32][32];
  __shared__ float red[256];
  __shared__ float sdt;
  const int t = threadIdx.x;
  float p = 0.f;
  for (int i = t; i < D_MODEL; i += 256) {
    float v = __expf(log_dt[i]);
    v = fminf(fmaxf(v, 1e-4f), 1.0f);
    p += v;
  }
  red[t] = p;
  __syncthreads();
  for (int s = 128; s > 0; s >>= 1) {
    if (t < s) red[t] += red[t + s];
    __syncthreads();
  }
  if (t == 0) sdt = red[0] * (1.0f / D_MODEL);
  __syncthreads();
  const float dt = sdt;
  for (int i = t; i < 1024; i += 256) {
    int r = i >> 5, c = i & 31;
    sM[r][c] = (r == c ? 1.f : 0.f) - 0.5f * dt * A[i];
  }
  __syncthreads();
  // X = M^{-1} via forward substitution (M is lower triangular, diag >= 1).
  if (t < 32) {
    const int j = t;
    float xcol[32];
#pragma unroll
    for (int i = 0; i < 32; i++) {
      float sacc = 0.f;
#pragma unroll
      for (int k = 0; k < 32; k++) {
        if (k < i) sacc -= sM[i][k] * xcol[k];
      }
      float num = (i == j ? 1.f : 0.f) + sacc;
      xcol[i] = (i >= j) ? num / sM[i][i] : 0.f;
    }
    for (int i = 0; i < 32; i++) sX[i][j] = xcol[i];
  }
  __syncthreads();
  // A_bar = (I + 0.5dt A) @ X
  for (int i = t; i < 1024; i += 256) {
    int r = i >> 5, c = i & 31;
    float s = 0.f;
    for (int k = 0; k < 32; k++) {
      float p2 = (r == k ? 1.f : 0.f) + 0.5f * dt * A[r * 32 + k];
      s += p2 * sX[k][c];
    }
    A_bar[i] = s;
  }
  // B_bar = dt * X @ B   (stored [n][d])
  for (int i = t; i < D_STATE * D_MODEL; i += 256) {
    int n = i >> 9, d = i & 511;
    float s = 0.f;
    for (int k = 0; k < 32; k++) s += sX[n][k] * B[k * D_MODEL + d];
    B_bar[i] = dt * s;
  }
}

// ---------------- K1c/d: CW = W@C (bf16, [e][n]), WD = W*D (bf16, [e][d]) ----------------
__global__ void k_weights(const float* __restrict__ C, const float* __restrict__ D,
                          const float* __restrict__ W,
                          bf16* __restrict__ CW, bf16* __restrict__ WD) {
  const int b = blockIdx.x, t = threadIdx.x;
  if (b < 64) {
    const int idx = b * 256 + t;  // 0..16383
    const int e = idx >> 5, n = idx & 31;
    float s = 0.f;
    for (int d = 0; d < D_MODEL; d++) s += W[e * D_MODEL + d] * C[d * D_STATE + n];
    CW[idx] = (bf16)s;
  } else {
    for (int i = (b - 64) * 256 + t; i < D_MODEL * D_MODEL; i += 64 * 256) {
      WD[i] = (bf16)(W[i] * D[i & 511]);
    }
  }
}

// ---------------- K2: uB = x @ B_bar^T; also emit x as bf16 ----------------
__global__ __launch_bounds__(256) void k_ub(const float* __restrict__ x,
                                            const float* __restrict__ B_bar,
                                            float* __restrict__ uB,
                                            bf16* __restrict__ xb) {
  __shared__ float xs[16 * 512];
  const int t = threadIdx.x;
  const long rb = (long)blockIdx.x * 16;
  const float* src = x + rb * D_MODEL;
  bf16* xdst = xb + rb * D_MODEL;
#pragma unroll
  for (int i = 0; i < 8; i++) {
    const int idx = i * 1024 + t * 4;
    const f32x4 v = *(const f32x4*)(src + idx);
    *(f32x4*)(xs + idx) = v;
    bf16x4 h;
    h[0] = (bf16)v[0]; h[1] = (bf16)v[1]; h[2] = (bf16)v[2]; h[3] = (bf16)v[3];
    *(bf16x4*)(xdst + idx) = h;
  }
  __syncthreads();
  const int n = t & 31, rr = t >> 5;  // rr in 0..7 -> rows rr and rr+8
  float acc0 = 0.f, acc1 = 0.f;
  const float* bp = B_bar + n * D_MODEL;
  for (int d = 0; d < D_MODEL; d += 4) {
    const f32x4 b4 = *(const f32x4*)(bp + d);
    const f32x4 xa = *(const f32x4*)(xs + rr * 512 + d);
    const f32x4 xc = *(const f32x4*)(xs + (rr + 8) * 512 + d);
#pragma unroll
    for (int q = 0; q < 4; q++) {
      acc0 = fmaf(xa[q], b4[q], acc0);
      acc1 = fmaf(xc[q], b4[q], acc1);
    }
  }
  uB[(rb + rr) * D_STATE + n] = acc0;
  uB[(rb + rr + 8) * D_STATE + n] = acc1;
}

// ---------------- K3: chunked tanh scan, LDS-broadcast state replication ----------------
// Per 32-lane group: one chain. Lane n owns state element n; each step it writes s_n
// to a 32-float LDS slot and reads the full state back as 8x ds_read_b128.
// 9 DS ops/step instead of 32 ds_bpermute.
#define CHUNK 64
#define BURN 96
#define STEPS (CHUNK + BURN)   // 160 serial steps per chain
#define NCHUNK (SEQ / CHUNK)   // 64 chunks per batch
__global__ __launch_bounds__(64) void k_scan(const float* __restrict__ uB,
                                             const float* __restrict__ A_bar,
                                             bf16* __restrict__ S,
                                             float* __restrict__ fs_out) {
  __shared__ float sbuf[64];          // 2 groups x 32 state elems
  const int lane = threadIdx.x;       // 0..63
  const int g = lane >> 5, n = lane & 31;
  const int chain = blockIdx.x * 2 + g;
  const int b = chain >> 6;           // NCHUNK=64 chunks per batch
  const int ch = chain & 63;
  const int cs = ch * CHUNK;
  const int t0 = cs - BURN;           // may be negative (u treated as 0 there)
  const int ce = cs + CHUNK;

  float a[32];
#pragma unroll
  for (int k = 0; k < 32; k += 4) {
    const f32x4 v = *(const f32x4*)(A_bar + n * 32 + k);
    a[k] = v[0]; a[k + 1] = v[1]; a[k + 2] = v[2]; a[k + 3] = v[3];
  }

  const float* ub = uB + (long)b * SEQ * D_STATE + n;
  bf16* sp = S + ((long)b * SEQ + cs) * D_STATE + n;
  float* myslot = &sbuf[g * 32];

  float s = 0.f;
  float ubuf[8], unext[8];
#pragma unroll
  for (int i = 0; i < 8; i++) {
    const int t = t0 + i;
    ubuf[i] = (t >= 0) ? ub[(long)t * D_STATE] : 0.f;
  }

  for (int tg = t0; tg < ce; tg += 8) {
    const int tn = tg + 8;
#pragma unroll
    for (int i = 0; i < 8; i++) {
      const int t = tn + i;
      unext[i] = (t >= 0 && t < ce) ? ub[(long)t * D_STATE] : 0.f;
    }
#pragma unroll
    for (int i = 0; i < 8; i++) {
      const int t = tg + i;
      myslot[n] = s;  // ds_write_b32; wave-ordered before the reads below
      const f32x4 s0 = *(const f32x4*)(myslot + 0);
      const f32x4 s1 = *(const f32x4*)(myslot + 4);
      const f32x4 s2 = *(const f32x4*)(myslot + 8);
      const f32x4 s3 = *(const f32x4*)(myslot + 12);
      const f32x4 s4 = *(const f32x4*)(myslot + 16);
      const f32x4 s5 = *(const f32x4*)(myslot + 20);
      const f32x4 s6 = *(const f32x4*)(myslot + 24);
      const f32x4 s7 = *(const f32x4*)(myslot + 28);
      float acc0 = ubuf[i], acc1 = 0.f, acc2 = 0.f, acc3 = 0.f;
#pragma unroll
      for (int q = 0; q < 4; q++) {
        acc0 = fmaf(a[0 + q],  s0[q], acc0);
        acc1 = fmaf(a[4 + q],  s1[q], acc1);
        acc2 = fmaf(a[8 + q],  s2[q], acc2);
        acc3 = fmaf(a[12 + q], s3[q], acc3);
        acc0 = fmaf(a[16 + q], s4[q], acc0);
        acc1 = fmaf(a[20 + q], s5[q], acc1);
        acc2 = fmaf(a[24 + q], s6[q], acc2);
        acc3 = fmaf(a[28 + q], s7[q], acc3);
      }
      const float z = (acc0 + acc1) + (acc2 + acc3);
      const float e = __expf(2.f * z);
      const float r = __builtin_amdgcn_rcpf(e + 1.f);
      s = fmaf(-2.f, r, 1.f);
      if (t >= cs) sp[(long)(t - cs) * D_STATE] = (bf16)s;
    }
#pragma unroll
    for (int i = 0; i < 8; i++) ubuf[i] = unext[i];
  }
  if (ch == NCHUNK - 1) fs_out[b * D_STATE + n] = s;
}

// ---------------- K5: out = S@CW^T + xb@WD^T + b  (bf16 MFMA, 128x128 tile) ----------------
__device__ __forceinline__ void stage_tile(const void* gbase, long row0, long rowStrideB,
                                           int kByte, void* lds, int w, int lane) {
#pragma unroll
  for (int j = 0; j < 2; j++) {
    const int base_off = (w << 11) + (j << 10);
    const int boff = base_off + (lane << 4);
    const int r = boff >> 6;   // 64B per tile row (32 bf16)
    const int cb = boff & 63;
    const char* src = (const char*)gbase + (row0 + r) * rowStrideB + kByte + cb;
    __builtin_amdgcn_global_load_lds(
        (const __attribute__((address_space(1))) void*)src,
        (__attribute__((address_space(3))) void*)((char*)lds + base_off), 16, 0, 0);
  }
}

__global__ __launch_bounds__(256) void k_out(const bf16* __restrict__ xb,
                                             const bf16* __restrict__ WD,
                                             const bf16* __restrict__ Sb,
                                             const bf16* __restrict__ CW,
                                             const float* __restrict__ bias,
                                             float* __restrict__ out) {
  __shared__ bf16 As[128 * 32];
  __shared__ bf16 Bs[128 * 32];
  const int tid = threadIdx.x;
  const int w = tid >> 6, lane = tid & 63;
  const int bm = blockIdx.x >> 2, bn = blockIdx.x & 3;
  const long rowbase = (long)bm * 128;
  const long colbase = (long)bn * 128;
  const int wr = w >> 1, wc = w & 1;
  const int l15 = lane & 15, kg = lane >> 4;

  f32x4 acc[4][4];
#pragma unroll
  for (int m = 0; m < 4; m++)
#pragma unroll
    for (int n = 0; n < 4; n++) acc[m][n] = (f32x4)(0.0f);

  const int aoff = (wr * 64 + l15) * 32 + kg * 8;
  const int boff = (wc * 64 + l15) * 32 + kg * 8;

  for (int kt = 0; kt < 17; kt++) {
    if (kt < 16) {
      stage_tile(xb, rowbase, 1024, kt * 64, As, w, lane);
      stage_tile(WD, colbase, 1024, kt * 64, Bs, w, lane);
    } else {
      stage_tile(Sb, rowbase, 64, 0, As, w, lane);
      stage_tile(CW, colbase, 64, 0, Bs, w, lane);
    }
    __syncthreads();
    bf16x8 af[4], bfr[4];
#pragma unroll
    for (int m = 0; m < 4; m++) af[m] = *(const bf16x8*)&As[aoff + m * 16 * 32];
#pragma unroll
    for (int n = 0; n < 4; n++) bfr[n] = *(const bf16x8*)&Bs[boff + n * 16 * 32];
#pragma unroll
    for (int m = 0; m < 4; m++)
#pragma unroll
      for (int n = 0; n < 4; n++)
        acc[m][n] = __builtin_amdgcn_mfma_f32_16x16x32_bf16(af[m], bfr[n], acc[m][n], 0, 0, 0);
    __syncthreads();
  }
#pragma unroll
  for (int n = 0; n < 4; n++) {
    const int e = (int)colbase + wc * 64 + n * 16 + l15;
    const float bv = bias[e];
#pragma unroll
    for (int m = 0; m < 4; m++) {
      const long r0 = rowbase + wr * 64 + m * 16 + kg * 4;
      const f32x4 v = acc[m][n];
#pragma unroll
      for (int jj = 0; jj < 4; jj++) out[(r0 + jj) * (long)D_MODEL + e] = v[jj] + bv;
    }
  }
}

extern "C" void kernel_launch(void* const* d_in, const int* in_sizes, int n_in,
                              void* d_out, int out_size, void* d_ws, size_t ws_size,
                              hipStream_t stream) {
  const float* x      = (const float*)d_in[0];
  const float* A      = (const float*)d_in[1];
  const float* B      = (const float*)d_in[2];
  const float* C      = (const float*)d_in[3];
  const float* D      = (const float*)d_in[4];
  const float* log_dt = (const float*)d_in[5];
  const float* W      = (const float*)d_in[6];
  const float* b_out  = (const float*)d_in[7];
  float* out = (float*)d_out;
  float* fs  = out + (long)MROWS * D_MODEL;  // final_state (8x32) after y

  char* ws = (char*)d_ws;
  float* A_bar = (float*)(ws + 0);                    // 4 KB
  float* B_bar = (float*)(ws + (4L << 10));           // 64 KB
  bf16*  CW    = (bf16*)(ws + (68L << 10));           // 32 KB
  bf16*  WD    = (bf16*)(ws + (100L << 10));          // 512 KB
  bf16*  Sb    = (bf16*)(ws + (612L << 10));          // 2 MB
  float* uB    = (float*)(ws + (2660L << 10));        // 4 MB
  bf16*  xb    = (bf16*)(ws + (6756L << 10));         // 32 MB   (total ~38.6 MB)

  k_precompute<<<dim3(1), dim3(256), 0, stream>>>(A, B, log_dt, A_bar, B_bar);
  k_weights<<<dim3(128), dim3(256), 0, stream>>>(C, D, W, CW, WD);
  k_ub<<<dim3(MROWS / 16), dim3(256), 0, stream>>>(x, B_bar, uB, xb);
  k_scan<<<dim3(BATCH * NCHUNK / 2), dim3(64), 0, stream>>>(uB, A_bar, Sb, fs);
  k_out<<<dim3((MROWS / 128) * (D_MODEL / 128)), dim3(256), 0, stream>>>(xb, WD, Sb, CW, b_out, out);
}

// Round 3
// 147.946 us; speedup vs baseline: 3.3762x; 1.6636x over previous
//
#include <hip/hip_runtime.h>
#include <hip/hip_bf16.h>

#define D_MODEL 512
#define D_STATE 32
#define BATCH 8
#define SEQ 4096
#define MROWS (BATCH * SEQ)

typedef __bf16 bf16;
typedef __bf16 bf16x4 __attribute__((ext_vector_type(4)));
typedef __bf16 bf16x8 __attribute__((ext_vector_type(8)));
typedef float f32x4 __attribute__((ext_vector_type(4)));

// ---------------- K1: dt, inv(I-0.5dt A) (lower-tri), A_bar, packed B_hi/B_lo ----------------
// Packed B layout (fragment-direct for 16x16x32 MFMA B-operand):
//   p = ((kt*4 + kg)*32 + n)*8 + j   holds  B_bar[n][kt*32 + kg*8 + j]
__global__ void k_precompute(const float* __restrict__ A, const float* __restrict__ B,
                             const float* __restrict__ log_dt,
                             float* __restrict__ A_bar,
                             bf16* __restrict__ Bhi, bf16* __restrict__ Blo) {
  __shared__ float sM[32][32];
  __shared__ float sX[32][32];
  __shared__ float sB[32][512];   // 64 KB staged copy of B
  __shared__ float red[256];
  __shared__ float sdt;
  const int t = threadIdx.x;
  float p = 0.f;
  for (int i = t; i < D_MODEL; i += 256) {
    float v = __expf(log_dt[i]);
    v = fminf(fmaxf(v, 1e-4f), 1.0f);
    p += v;
  }
  red[t] = p;
  __syncthreads();
  for (int s = 128; s > 0; s >>= 1) {
    if (t < s) red[t] += red[t + s];
    __syncthreads();
  }
  if (t == 0) sdt = red[0] * (1.0f / D_MODEL);
  __syncthreads();
  const float dt = sdt;
  for (int i = t; i < 1024; i += 256) {
    int r = i >> 5, c = i & 31;
    sM[r][c] = (r == c ? 1.f : 0.f) - 0.5f * dt * A[i];
  }
  // stage B into LDS (coalesced)
  for (int i = t; i < D_STATE * D_MODEL; i += 256) ((float*)sB)[i] = B[i];
  __syncthreads();
  // X = M^{-1} via forward substitution (M lower triangular, diag >= 1).
  if (t < 32) {
    const int j = t;
    float xcol[32];
#pragma unroll
    for (int i = 0; i < 32; i++) {
      float sacc = 0.f;
#pragma unroll
      for (int k = 0; k < 32; k++) {
        if (k < i) sacc -= sM[i][k] * xcol[k];
      }
      float num = (i == j ? 1.f : 0.f) + sacc;
      xcol[i] = (i >= j) ? num / sM[i][i] : 0.f;
    }
    for (int i = 0; i < 32; i++) sX[i][j] = xcol[i];
  }
  __syncthreads();
  // A_bar = (I + 0.5dt A) @ X
  for (int i = t; i < 1024; i += 256) {
    int r = i >> 5, c = i & 31;
    float s = 0.f;
    for (int k = 0; k < 32; k++) {
      float p2 = (r == k ? 1.f : 0.f) + 0.5f * dt * A[r * 32 + k];
      s += p2 * sX[k][c];
    }
    A_bar[i] = s;
  }
  // Packed B_bar = dt * X @ B, split hi/lo bf16
  for (int i = t; i < D_STATE * D_MODEL; i += 256) {
    const int j = i & 7, n = (i >> 3) & 31, kg = (i >> 8) & 3, kt = i >> 10;
    const int k = kt * 32 + kg * 8 + j;
    float s = 0.f;
#pragma unroll
    for (int kk = 0; kk < 32; kk++) s += sX[n][kk] * sB[kk][k];
    s *= dt;
    const bf16 hi = (bf16)s;
    const float lo = s - (float)hi;
    Bhi[i] = hi;
    Blo[i] = (bf16)lo;
  }
}

// ---------------- K1c/d: CW = W@C (bf16, [e][n]), WD = W*D (bf16, [e][d]) ----------------
__global__ void k_weights(const float* __restrict__ C, const float* __restrict__ D,
                          const float* __restrict__ W,
                          bf16* __restrict__ CW, bf16* __restrict__ WD) {
  const int b = blockIdx.x, t = threadIdx.x;
  if (b < 64) {
    const int idx = b * 256 + t;  // 0..16383
    const int e = idx >> 5, n = idx & 31;
    float s = 0.f;
    for (int d = 0; d < D_MODEL; d++) s += W[e * D_MODEL + d] * C[d * D_STATE + n];
    CW[idx] = (bf16)s;
  } else {
    for (int i = (b - 64) * 256 + t; i < D_MODEL * D_MODEL; i += 64 * 256) {
      WD[i] = (bf16)(W[i] * D[i & 511]);
    }
  }
}

// ---------------- K2: uB = xb @ (B_hi+B_lo)^T via MFMA; also emits xb ----------------
// 256 blocks x 256 threads; 128-row tile; kt loop over K in chunks of 32.
// Double-buffered LDS bf16 x-tile, register prefetch across the single barrier.
__global__ __launch_bounds__(256) void k_ub(const float* __restrict__ x,
                                            const bf16* __restrict__ Bhi,
                                            const bf16* __restrict__ Blo,
                                            float* __restrict__ uB,
                                            bf16* __restrict__ xb) {
  __shared__ bf16 As[2][128][32];
  const int tid = threadIdx.x;
  const int w = tid >> 6, lane = tid & 63;
  const int l15 = lane & 15, kg = lane >> 4;
  const long rowbase = (long)blockIdx.x * 128;
  const int lrow = tid >> 1;
  const int lcol = (tid & 1) * 16;
  const float* xp0 = x + (rowbase + lrow) * D_MODEL + lcol;
  bf16* xo0 = xb + (rowbase + lrow) * D_MODEL + lcol;

  f32x4 acc[2][2];
#pragma unroll
  for (int m = 0; m < 2; m++)
#pragma unroll
    for (int n = 0; n < 2; n++) acc[m][n] = (f32x4)(0.0f);

  f32x4 v[4], vn[4];
#pragma unroll
  for (int j = 0; j < 4; j++) v[j] = *(const f32x4*)(xp0 + j * 4);

#pragma unroll
  for (int kt = 0; kt < 16; kt++) {
    const int buf = kt & 1;
    bf16x8 h0, h1;
#pragma unroll
    for (int q = 0; q < 4; q++) {
      h0[q] = (bf16)v[0][q]; h0[q + 4] = (bf16)v[1][q];
      h1[q] = (bf16)v[2][q]; h1[q + 4] = (bf16)v[3][q];
    }
    *(bf16x8*)(xo0 + kt * 32) = h0;
    *(bf16x8*)(xo0 + kt * 32 + 8) = h1;
    *(bf16x8*)(&As[buf][lrow][lcol]) = h0;
    *(bf16x8*)(&As[buf][lrow][lcol + 8]) = h1;
    if (kt < 15) {
#pragma unroll
      for (int j = 0; j < 4; j++) vn[j] = *(const f32x4*)(xp0 + (kt + 1) * 32 + j * 4);
    }
    __syncthreads();
    const bf16x8 af0 = *(const bf16x8*)(&As[buf][w * 32 + l15][kg * 8]);
    const bf16x8 af1 = *(const bf16x8*)(&As[buf][w * 32 + 16 + l15][kg * 8]);
    const int bo = ((kt * 4 + kg) * 32 + l15) * 8;
    const bf16x8 bh0 = *(const bf16x8*)(Bhi + bo);
    const bf16x8 bh1 = *(const bf16x8*)(Bhi + bo + 128);
    const bf16x8 bl0 = *(const bf16x8*)(Blo + bo);
    const bf16x8 bl1 = *(const bf16x8*)(Blo + bo + 128);
    acc[0][0] = __builtin_amdgcn_mfma_f32_16x16x32_bf16(af0, bh0, acc[0][0], 0, 0, 0);
    acc[0][0] = __builtin_amdgcn_mfma_f32_16x16x32_bf16(af0, bl0, acc[0][0], 0, 0, 0);
    acc[0][1] = __builtin_amdgcn_mfma_f32_16x16x32_bf16(af0, bh1, acc[0][1], 0, 0, 0);
    acc[0][1] = __builtin_amdgcn_mfma_f32_16x16x32_bf16(af0, bl1, acc[0][1], 0, 0, 0);
    acc[1][0] = __builtin_amdgcn_mfma_f32_16x16x32_bf16(af1, bh0, acc[1][0], 0, 0, 0);
    acc[1][0] = __builtin_amdgcn_mfma_f32_16x16x32_bf16(af1, bl0, acc[1][0], 0, 0, 0);
    acc[1][1] = __builtin_amdgcn_mfma_f32_16x16x32_bf16(af1, bh1, acc[1][1], 0, 0, 0);
    acc[1][1] = __builtin_amdgcn_mfma_f32_16x16x32_bf16(af1, bl1, acc[1][1], 0, 0, 0);
#pragma unroll
    for (int j = 0; j < 4; j++) v[j] = vn[j];
  }
  // epilogue: C/D layout col=lane&15, row=(lane>>4)*4+reg
#pragma unroll
  for (int mf = 0; mf < 2; mf++)
#pragma unroll
    for (int nf = 0; nf < 2; nf++) {
      const long r0 = rowbase + w * 32 + mf * 16 + kg * 4;
      const int n = nf * 16 + l15;
#pragma unroll
      for (int jj = 0; jj < 4; jj++)
        uB[(r0 + jj) * D_STATE + n] = acc[mf][nf][jj];
    }
}

// ---------------- K3: chunked tanh scan, LDS-broadcast state replication ----------------
#define CHUNK 64
#define BURN 96
#define NCHUNK (SEQ / CHUNK)   // 64 chunks per batch
__global__ __launch_bounds__(64) void k_scan(const float* __restrict__ uB,
                                             const float* __restrict__ A_bar,
                                             bf16* __restrict__ S,
                                             float* __restrict__ fs_out) {
  __shared__ float sbuf[64];          // 2 groups x 32 state elems
  const int lane = threadIdx.x;       // 0..63
  const int g = lane >> 5, n = lane & 31;
  const int chain = blockIdx.x * 2 + g;
  const int b = chain >> 6;
  const int ch = chain & 63;
  const int cs = ch * CHUNK;
  const int t0 = cs - BURN;           // may be negative (u treated as 0 there)
  const int ce = cs + CHUNK;

  float a[32];
#pragma unroll
  for (int k = 0; k < 32; k += 4) {
    const f32x4 v = *(const f32x4*)(A_bar + n * 32 + k);
    a[k] = v[0]; a[k + 1] = v[1]; a[k + 2] = v[2]; a[k + 3] = v[3];
  }

  const float* ub = uB + (long)b * SEQ * D_STATE + n;
  bf16* sp = S + ((long)b * SEQ + cs) * D_STATE + n;
  float* myslot = &sbuf[g * 32];

  float s = 0.f;
  float ubuf[8], unext[8];
#pragma unroll
  for (int i = 0; i < 8; i++) {
    const int t = t0 + i;
    ubuf[i] = (t >= 0) ? ub[(long)t * D_STATE] : 0.f;
  }

  for (int tg = t0; tg < ce; tg += 8) {
    const int tn = tg + 8;
#pragma unroll
    for (int i = 0; i < 8; i++) {
      const int t = tn + i;
      unext[i] = (t >= 0 && t < ce) ? ub[(long)t * D_STATE] : 0.f;
    }
#pragma unroll
    for (int i = 0; i < 8; i++) {
      const int t = tg + i;
      myslot[n] = s;  // ds_write_b32; wave-ordered before the reads below
      const f32x4 s0 = *(const f32x4*)(myslot + 0);
      const f32x4 s1 = *(const f32x4*)(myslot + 4);
      const f32x4 s2 = *(const f32x4*)(myslot + 8);
      const f32x4 s3 = *(const f32x4*)(myslot + 12);
      const f32x4 s4 = *(const f32x4*)(myslot + 16);
      const f32x4 s5 = *(const f32x4*)(myslot + 20);
      const f32x4 s6 = *(const f32x4*)(myslot + 24);
      const f32x4 s7 = *(const f32x4*)(myslot + 28);
      float acc0 = ubuf[i], acc1 = 0.f, acc2 = 0.f, acc3 = 0.f;
#pragma unroll
      for (int q = 0; q < 4; q++) {
        acc0 = fmaf(a[0 + q],  s0[q], acc0);
        acc1 = fmaf(a[4 + q],  s1[q], acc1);
        acc2 = fmaf(a[8 + q],  s2[q], acc2);
        acc3 = fmaf(a[12 + q], s3[q], acc3);
        acc0 = fmaf(a[16 + q], s4[q], acc0);
        acc1 = fmaf(a[20 + q], s5[q], acc1);
        acc2 = fmaf(a[24 + q], s6[q], acc2);
        acc3 = fmaf(a[28 + q], s7[q], acc3);
      }
      const float z = (acc0 + acc1) + (acc2 + acc3);
      const float e = __expf(2.f * z);
      const float r = __builtin_amdgcn_rcpf(e + 1.f);
      s = fmaf(-2.f, r, 1.f);
      if (t >= cs) sp[(long)(t - cs) * D_STATE] = (bf16)s;
    }
#pragma unroll
    for (int i = 0; i < 8; i++) ubuf[i] = unext[i];
  }
  if (ch == NCHUNK - 1) fs_out[b * D_STATE + n] = s;
}

// ---------------- K5: out = S@CW^T + xb@WD^T + b  (bf16 MFMA, 128x128 tile) ----------------
__device__ __forceinline__ void stage_tile(const void* gbase, long row0, long rowStrideB,
                                           int kByte, void* lds, int w, int lane) {
#pragma unroll
  for (int j = 0; j < 2; j++) {
    const int base_off = (w << 11) + (j << 10);
    const int boff = base_off + (lane << 4);
    const int r = boff >> 6;   // 64B per tile row (32 bf16)
    const int cb = boff & 63;
    const char* src = (const char*)gbase + (row0 + r) * rowStrideB + kByte + cb;
    __builtin_amdgcn_global_load_lds(
        (const __attribute__((address_space(1))) void*)src,
        (__attribute__((address_space(3))) void*)((char*)lds + base_off), 16, 0, 0);
  }
}

__global__ __launch_bounds__(256) void k_out(const bf16* __restrict__ xb,
                                             const bf16* __restrict__ WD,
                                             const bf16* __restrict__ Sb,
                                             const bf16* __restrict__ CW,
                                             const float* __restrict__ bias,
                                             float* __restrict__ out) {
  __shared__ bf16 As[128 * 32];
  __shared__ bf16 Bs[128 * 32];
  const int tid = threadIdx.x;
  const int w = tid >> 6, lane = tid & 63;
  const int bm = blockIdx.x >> 2, bn = blockIdx.x & 3;
  const long rowbase = (long)bm * 128;
  const long colbase = (long)bn * 128;
  const int wr = w >> 1, wc = w & 1;
  const int l15 = lane & 15, kg = lane >> 4;

  f32x4 acc[4][4];
#pragma unroll
  for (int m = 0; m < 4; m++)
#pragma unroll
    for (int n = 0; n < 4; n++) acc[m][n] = (f32x4)(0.0f);

  const int aoff = (wr * 64 + l15) * 32 + kg * 8;
  const int boff = (wc * 64 + l15) * 32 + kg * 8;

  for (int kt = 0; kt < 17; kt++) {
    if (kt < 16) {
      stage_tile(xb, rowbase, 1024, kt * 64, As, w, lane);
      stage_tile(WD, colbase, 1024, kt * 64, Bs, w, lane);
    } else {
      stage_tile(Sb, rowbase, 64, 0, As, w, lane);
      stage_tile(CW, colbase, 64, 0, Bs, w, lane);
    }
    __syncthreads();
    bf16x8 af[4], bfr[4];
#pragma unroll
    for (int m = 0; m < 4; m++) af[m] = *(const bf16x8*)&As[aoff + m * 16 * 32];
#pragma unroll
    for (int n = 0; n < 4; n++) bfr[n] = *(const bf16x8*)&Bs[boff + n * 16 * 32];
#pragma unroll
    for (int m = 0; m < 4; m++)
#pragma unroll
      for (int n = 0; n < 4; n++)
        acc[m][n] = __builtin_amdgcn_mfma_f32_16x16x32_bf16(af[m], bfr[n], acc[m][n], 0, 0, 0);
    __syncthreads();
  }
#pragma unroll
  for (int n = 0; n < 4; n++) {
    const int e = (int)colbase + wc * 64 + n * 16 + l15;
    const float bv = bias[e];
#pragma unroll
    for (int m = 0; m < 4; m++) {
      const long r0 = rowbase + wr * 64 + m * 16 + kg * 4;
      const f32x4 v = acc[m][n];
#pragma unroll
      for (int jj = 0; jj < 4; jj++) out[(r0 + jj) * (long)D_MODEL + e] = v[jj] + bv;
    }
  }
}

extern "C" void kernel_launch(void* const* d_in, const int* in_sizes, int n_in,
                              void* d_out, int out_size, void* d_ws, size_t ws_size,
                              hipStream_t stream) {
  const float* x      = (const float*)d_in[0];
  const float* A      = (const float*)d_in[1];
  const float* B      = (const float*)d_in[2];
  const float* C      = (const float*)d_in[3];
  const float* D      = (const float*)d_in[4];
  const float* log_dt = (const float*)d_in[5];
  const float* W      = (const float*)d_in[6];
  const float* b_out  = (const float*)d_in[7];
  float* out = (float*)d_out;
  float* fs  = out + (long)MROWS * D_MODEL;  // final_state (8x32) after y

  char* ws = (char*)d_ws;
  float* A_bar = (float*)(ws + 0);                    // 4 KB
  bf16*  Bhi   = (bf16*)(ws + (4L << 10));            // 32 KB
  bf16*  Blo   = (bf16*)(ws + (36L << 10));           // 32 KB
  bf16*  CW    = (bf16*)(ws + (68L << 10));           // 32 KB
  bf16*  WD    = (bf16*)(ws + (100L << 10));          // 512 KB
  bf16*  Sb    = (bf16*)(ws + (612L << 10));          // 2 MB
  float* uB    = (float*)(ws + (2660L << 10));        // 4 MB
  bf16*  xb    = (bf16*)(ws + (6756L << 10));         // 32 MB   (total ~38.6 MB)

  k_precompute<<<dim3(1), dim3(256), 0, stream>>>(A, B, log_dt, A_bar, Bhi, Blo);
  k_weights<<<dim3(128), dim3(256), 0, stream>>>(C, D, W, CW, WD);
  k_ub<<<dim3(MROWS / 128), dim3(256), 0, stream>>>(x, Bhi, Blo, uB, xb);
  k_scan<<<dim3(BATCH * NCHUNK / 2), dim3(64), 0, stream>>>(uB, A_bar, Sb, fs);
  k_out<<<dim3((MROWS / 128) * (D_MODEL / 128)), dim3(256), 0, stream>>>(xb, WD, Sb, CW, b_out, out);
}

// Round 4
// 142.277 us; speedup vs baseline: 3.5107x; 1.0398x over previous
//
#include <hip/hip_runtime.h>
#include <hip/hip_bf16.h>

#define D_MODEL 512
#define D_STATE 32
#define BATCH 8
#define SEQ 4096
#define MROWS (BATCH * SEQ)

typedef __bf16 bf16;
typedef __bf16 bf16x4 __attribute__((ext_vector_type(4)));
typedef __bf16 bf16x8 __attribute__((ext_vector_type(8)));
typedef float f32x4 __attribute__((ext_vector_type(4)));

// ---------------- K1: dt, inv(I-0.5dt A) (lower-tri), A_bar, packed B_hi/B_lo ----------------
// Packed B layout (fragment-direct for 16x16x32 MFMA B-operand):
//   p = ((kt*4 + kg)*32 + n)*8 + j   holds  B_bar[n][kt*32 + kg*8 + j]
__global__ void k_precompute(const float* __restrict__ A, const float* __restrict__ B,
                             const float* __restrict__ log_dt,
                             float* __restrict__ A_bar,
                             bf16* __restrict__ Bhi, bf16* __restrict__ Blo) {
  __shared__ float sM[32][32];
  __shared__ float sX[32][32];
  __shared__ float sB[32][512];   // 64 KB staged copy of B
  __shared__ float red[256];
  __shared__ float sdt;
  const int t = threadIdx.x;
  float p = 0.f;
  for (int i = t; i < D_MODEL; i += 256) {
    float v = __expf(log_dt[i]);
    v = fminf(fmaxf(v, 1e-4f), 1.0f);
    p += v;
  }
  red[t] = p;
  __syncthreads();
  for (int s = 128; s > 0; s >>= 1) {
    if (t < s) red[t] += red[t + s];
    __syncthreads();
  }
  if (t == 0) sdt = red[0] * (1.0f / D_MODEL);
  __syncthreads();
  const float dt = sdt;
  for (int i = t; i < 1024; i += 256) {
    int r = i >> 5, c = i & 31;
    sM[r][c] = (r == c ? 1.f : 0.f) - 0.5f * dt * A[i];
  }
  // stage B into LDS (coalesced)
  for (int i = t; i < D_STATE * D_MODEL; i += 256) ((float*)sB)[i] = B[i];
  __syncthreads();
  // X = M^{-1} via forward substitution (M lower triangular, diag >= 1).
  if (t < 32) {
    const int j = t;
    float xcol[32];
#pragma unroll
    for (int i = 0; i < 32; i++) {
      float sacc = 0.f;
#pragma unroll
      for (int k = 0; k < 32; k++) {
        if (k < i) sacc -= sM[i][k] * xcol[k];
      }
      float num = (i == j ? 1.f : 0.f) + sacc;
      xcol[i] = (i >= j) ? num / sM[i][i] : 0.f;
    }
    for (int i = 0; i < 32; i++) sX[i][j] = xcol[i];
  }
  __syncthreads();
  // A_bar = (I + 0.5dt A) @ X
  for (int i = t; i < 1024; i += 256) {
    int r = i >> 5, c = i & 31;
    float s = 0.f;
    for (int k = 0; k < 32; k++) {
      float p2 = (r == k ? 1.f : 0.f) + 0.5f * dt * A[r * 32 + k];
      s += p2 * sX[k][c];
    }
    A_bar[i] = s;
  }
  // Packed B_bar = dt * X @ B, split hi/lo bf16
  for (int i = t; i < D_STATE * D_MODEL; i += 256) {
    const int j = i & 7, n = (i >> 3) & 31, kg = (i >> 8) & 3, kt = i >> 10;
    const int k = kt * 32 + kg * 8 + j;
    float s = 0.f;
#pragma unroll
    for (int kk = 0; kk < 32; kk++) s += sX[n][kk] * sB[kk][k];
    s *= dt;
    const bf16 hi = (bf16)s;
    const float lo = s - (float)hi;
    Bhi[i] = hi;
    Blo[i] = (bf16)lo;
  }
}

// ---------------- K1c/d: CW = W@C (bf16, [e][n]), WD = W*D (bf16, [e][d]) ----------------
__global__ void k_weights(const float* __restrict__ C, const float* __restrict__ D,
                          const float* __restrict__ W,
                          bf16* __restrict__ CW, bf16* __restrict__ WD) {
  const int b = blockIdx.x, t = threadIdx.x;
  if (b < 64) {
    const int idx = b * 256 + t;  // 0..16383
    const int e = idx >> 5, n = idx & 31;
    float s = 0.f;
    for (int d = 0; d < D_MODEL; d++) s += W[e * D_MODEL + d] * C[d * D_STATE + n];
    CW[idx] = (bf16)s;
  } else {
    for (int i = (b - 64) * 256 + t; i < D_MODEL * D_MODEL; i += 64 * 256) {
      WD[i] = (bf16)(W[i] * D[i & 511]);
    }
  }
}

// ---------------- K2: uB = xb @ (B_hi+B_lo)^T via MFMA; also emits xb ----------------
__global__ __launch_bounds__(256) void k_ub(const float* __restrict__ x,
                                            const bf16* __restrict__ Bhi,
                                            const bf16* __restrict__ Blo,
                                            float* __restrict__ uB,
                                            bf16* __restrict__ xb) {
  __shared__ bf16 As[2][128][32];
  const int tid = threadIdx.x;
  const int w = tid >> 6, lane = tid & 63;
  const int l15 = lane & 15, kg = lane >> 4;
  const long rowbase = (long)blockIdx.x * 128;
  const int lrow = tid >> 1;
  const int lcol = (tid & 1) * 16;
  const float* xp0 = x + (rowbase + lrow) * D_MODEL + lcol;
  bf16* xo0 = xb + (rowbase + lrow) * D_MODEL + lcol;

  f32x4 acc[2][2];
#pragma unroll
  for (int m = 0; m < 2; m++)
#pragma unroll
    for (int n = 0; n < 2; n++) acc[m][n] = (f32x4)(0.0f);

  f32x4 v[4], vn[4];
#pragma unroll
  for (int j = 0; j < 4; j++) v[j] = *(const f32x4*)(xp0 + j * 4);

#pragma unroll
  for (int kt = 0; kt < 16; kt++) {
    const int buf = kt & 1;
    bf16x8 h0, h1;
#pragma unroll
    for (int q = 0; q < 4; q++) {
      h0[q] = (bf16)v[0][q]; h0[q + 4] = (bf16)v[1][q];
      h1[q] = (bf16)v[2][q]; h1[q + 4] = (bf16)v[3][q];
    }
    *(bf16x8*)(xo0 + kt * 32) = h0;
    *(bf16x8*)(xo0 + kt * 32 + 8) = h1;
    *(bf16x8*)(&As[buf][lrow][lcol]) = h0;
    *(bf16x8*)(&As[buf][lrow][lcol + 8]) = h1;
    if (kt < 15) {
#pragma unroll
      for (int j = 0; j < 4; j++) vn[j] = *(const f32x4*)(xp0 + (kt + 1) * 32 + j * 4);
    }
    __syncthreads();
    const bf16x8 af0 = *(const bf16x8*)(&As[buf][w * 32 + l15][kg * 8]);
    const bf16x8 af1 = *(const bf16x8*)(&As[buf][w * 32 + 16 + l15][kg * 8]);
    const int bo = ((kt * 4 + kg) * 32 + l15) * 8;
    const bf16x8 bh0 = *(const bf16x8*)(Bhi + bo);
    const bf16x8 bh1 = *(const bf16x8*)(Bhi + bo + 128);
    const bf16x8 bl0 = *(const bf16x8*)(Blo + bo);
    const bf16x8 bl1 = *(const bf16x8*)(Blo + bo + 128);
    acc[0][0] = __builtin_amdgcn_mfma_f32_16x16x32_bf16(af0, bh0, acc[0][0], 0, 0, 0);
    acc[0][0] = __builtin_amdgcn_mfma_f32_16x16x32_bf16(af0, bl0, acc[0][0], 0, 0, 0);
    acc[0][1] = __builtin_amdgcn_mfma_f32_16x16x32_bf16(af0, bh1, acc[0][1], 0, 0, 0);
    acc[0][1] = __builtin_amdgcn_mfma_f32_16x16x32_bf16(af0, bl1, acc[0][1], 0, 0, 0);
    acc[1][0] = __builtin_amdgcn_mfma_f32_16x16x32_bf16(af1, bh0, acc[1][0], 0, 0, 0);
    acc[1][0] = __builtin_amdgcn_mfma_f32_16x16x32_bf16(af1, bl0, acc[1][0], 0, 0, 0);
    acc[1][1] = __builtin_amdgcn_mfma_f32_16x16x32_bf16(af1, bh1, acc[1][1], 0, 0, 0);
    acc[1][1] = __builtin_amdgcn_mfma_f32_16x16x32_bf16(af1, bl1, acc[1][1], 0, 0, 0);
#pragma unroll
    for (int j = 0; j < 4; j++) v[j] = vn[j];
  }
  // epilogue: C/D layout col=lane&15, row=(lane>>4)*4+reg
#pragma unroll
  for (int mf = 0; mf < 2; mf++)
#pragma unroll
    for (int nf = 0; nf < 2; nf++) {
      const long r0 = rowbase + w * 32 + mf * 16 + kg * 4;
      const int n = nf * 16 + l15;
#pragma unroll
      for (int jj = 0; jj < 4; jj++)
        uB[(r0 + jj) * D_STATE + n] = acc[mf][nf][jj];
    }
}

// ---------------- K3: chunked tanh scan, LDS-broadcast state replication ----------------
#define CHUNK 64
#define BURN 96
#define NCHUNK (SEQ / CHUNK)   // 64 chunks per batch
__global__ __launch_bounds__(64) void k_scan(const float* __restrict__ uB,
                                             const float* __restrict__ A_bar,
                                             bf16* __restrict__ S,
                                             float* __restrict__ fs_out) {
  __shared__ float sbuf[64];          // 2 groups x 32 state elems
  const int lane = threadIdx.x;       // 0..63
  const int g = lane >> 5, n = lane & 31;
  const int chain = blockIdx.x * 2 + g;
  const int b = chain >> 6;
  const int ch = chain & 63;
  const int cs = ch * CHUNK;
  const int t0 = cs - BURN;           // may be negative (u treated as 0 there)
  const int ce = cs + CHUNK;

  float a[32];
#pragma unroll
  for (int k = 0; k < 32; k += 4) {
    const f32x4 v = *(const f32x4*)(A_bar + n * 32 + k);
    a[k] = v[0]; a[k + 1] = v[1]; a[k + 2] = v[2]; a[k + 3] = v[3];
  }

  const float* ub = uB + (long)b * SEQ * D_STATE + n;
  bf16* sp = S + ((long)b * SEQ + cs) * D_STATE + n;
  float* myslot = &sbuf[g * 32];

  float s = 0.f;
  float ubuf[8], unext[8];
#pragma unroll
  for (int i = 0; i < 8; i++) {
    const int t = t0 + i;
    ubuf[i] = (t >= 0) ? ub[(long)t * D_STATE] : 0.f;
  }

  for (int tg = t0; tg < ce; tg += 8) {
    const int tn = tg + 8;
#pragma unroll
    for (int i = 0; i < 8; i++) {
      const int t = tn + i;
      unext[i] = (t >= 0 && t < ce) ? ub[(long)t * D_STATE] : 0.f;
    }
#pragma unroll
    for (int i = 0; i < 8; i++) {
      const int t = tg + i;
      myslot[n] = s;  // ds_write_b32; wave-ordered before the reads below
      const f32x4 s0 = *(const f32x4*)(myslot + 0);
      const f32x4 s1 = *(const f32x4*)(myslot + 4);
      const f32x4 s2 = *(const f32x4*)(myslot + 8);
      const f32x4 s3 = *(const f32x4*)(myslot + 12);
      const f32x4 s4 = *(const f32x4*)(myslot + 16);
      const f32x4 s5 = *(const f32x4*)(myslot + 20);
      const f32x4 s6 = *(const f32x4*)(myslot + 24);
      const f32x4 s7 = *(const f32x4*)(myslot + 28);
      float acc0 = ubuf[i], acc1 = 0.f, acc2 = 0.f, acc3 = 0.f;
#pragma unroll
      for (int q = 0; q < 4; q++) {
        acc0 = fmaf(a[0 + q],  s0[q], acc0);
        acc1 = fmaf(a[4 + q],  s1[q], acc1);
        acc2 = fmaf(a[8 + q],  s2[q], acc2);
        acc3 = fmaf(a[12 + q], s3[q], acc3);
        acc0 = fmaf(a[16 + q], s4[q], acc0);
        acc1 = fmaf(a[20 + q], s5[q], acc1);
        acc2 = fmaf(a[24 + q], s6[q], acc2);
        acc3 = fmaf(a[28 + q], s7[q], acc3);
      }
      const float z = (acc0 + acc1) + (acc2 + acc3);
      const float e = __expf(2.f * z);
      const float r = __builtin_amdgcn_rcpf(e + 1.f);
      s = fmaf(-2.f, r, 1.f);
      if (t >= cs) sp[(long)(t - cs) * D_STATE] = (bf16)s;
    }
#pragma unroll
    for (int i = 0; i < 8; i++) ubuf[i] = unext[i];
  }
  if (ch == NCHUNK - 1) fs_out[b * D_STATE + n] = s;
}

// ---------------- K5: out = S@CW^T + xb@WD^T + b  (bf16 MFMA, 128x128 tile) ----------------
// Double-buffered LDS, one barrier per K-tile, XCD-aware block swizzle,
// XOR slot-swizzle on the [128][32] tiles (pre-swizzled global source since
// global_load_lds writes linearly; read side applies the same XOR).
__device__ __forceinline__ void stage_tile(const void* gbase, long row0, long rowStrideB,
                                           int kByte, void* lds, int w, int lane) {
#pragma unroll
  for (int j = 0; j < 2; j++) {
    const int base_off = (w << 11) + (j << 10);
    const int boff = base_off + (lane << 4);   // physical LDS byte this lane fills
    const int r = boff >> 6;                   // tile row (64B per row: 32 bf16)
    const int s = (boff >> 4) & 3;             // physical 16B slot within row
    const int cb = ((s ^ (r & 3)) << 4);       // swizzled source slot
    const char* src = (const char*)gbase + (row0 + r) * rowStrideB + kByte + cb;
    __builtin_amdgcn_global_load_lds(
        (const __attribute__((address_space(1))) void*)src,
        (__attribute__((address_space(3))) void*)((char*)lds + base_off), 16, 0, 0);
  }
}

__global__ __launch_bounds__(256) void k_out(const bf16* __restrict__ xb,
                                             const bf16* __restrict__ WD,
                                             const bf16* __restrict__ Sb,
                                             const bf16* __restrict__ CW,
                                             const float* __restrict__ bias,
                                             float* __restrict__ out) {
  __shared__ bf16 As[2][128 * 32];
  __shared__ bf16 Bs[2][128 * 32];
  const int tid = threadIdx.x;
  const int w = tid >> 6, lane = tid & 63;
  // XCD-bijective swizzle: 1024 blocks, 8 XCDs -> each XCD owns 128 contiguous
  // logical tiles = 32 bm-rows x 4 bn (xb row-tile fetched by one XCD only).
  const int swz = (blockIdx.x & 7) * 128 + (blockIdx.x >> 3);
  const int bm = swz >> 2, bn = swz & 3;
  const long rowbase = (long)bm * 128;
  const long colbase = (long)bn * 128;
  const int wr = w >> 1, wc = w & 1;
  const int l15 = lane & 15, kg = lane >> 4;
  const int kgs = kg ^ (l15 & 3);  // swizzled read slot (row&3 == l15&3 here)

  f32x4 acc[4][4];
#pragma unroll
  for (int m = 0; m < 4; m++)
#pragma unroll
    for (int n = 0; n < 4; n++) acc[m][n] = (f32x4)(0.0f);

  const int aoff = (wr * 64 + l15) * 32 + kgs * 8;
  const int boff = (wc * 64 + l15) * 32 + kgs * 8;

  // stage tile ti into buffer b
  auto STAGE = [&](int ti, int b) {
    if (ti < 16) {
      stage_tile(xb, rowbase, 1024, ti * 64, &As[b][0], w, lane);
      stage_tile(WD, colbase, 1024, ti * 64, &Bs[b][0], w, lane);
    } else {
      stage_tile(Sb, rowbase, 64, 0, &As[b][0], w, lane);
      stage_tile(CW, colbase, 64, 0, &Bs[b][0], w, lane);
    }
  };

  STAGE(0, 0);
  __syncthreads();
#pragma unroll 1
  for (int kt = 0; kt < 17; kt++) {
    const int cur = kt & 1;
    if (kt < 16) STAGE(kt + 1, cur ^ 1);
    bf16x8 af[4], bfr[4];
#pragma unroll
    for (int m = 0; m < 4; m++) af[m] = *(const bf16x8*)&As[cur][aoff + m * 16 * 32];
#pragma unroll
    for (int n = 0; n < 4; n++) bfr[n] = *(const bf16x8*)&Bs[cur][boff + n * 16 * 32];
#pragma unroll
    for (int m = 0; m < 4; m++)
#pragma unroll
      for (int n = 0; n < 4; n++)
        acc[m][n] = __builtin_amdgcn_mfma_f32_16x16x32_bf16(af[m], bfr[n], acc[m][n], 0, 0, 0);
    __syncthreads();
  }
#pragma unroll
  for (int n = 0; n < 4; n++) {
    const int e = (int)colbase + wc * 64 + n * 16 + l15;
    const float bv = bias[e];
#pragma unroll
    for (int m = 0; m < 4; m++) {
      const long r0 = rowbase + wr * 64 + m * 16 + kg * 4;
      const f32x4 v = acc[m][n];
#pragma unroll
      for (int jj = 0; jj < 4; jj++) out[(r0 + jj) * (long)D_MODEL + e] = v[jj] + bv;
    }
  }
}

extern "C" void kernel_launch(void* const* d_in, const int* in_sizes, int n_in,
                              void* d_out, int out_size, void* d_ws, size_t ws_size,
                              hipStream_t stream) {
  const float* x      = (const float*)d_in[0];
  const float* A      = (const float*)d_in[1];
  const float* B      = (const float*)d_in[2];
  const float* C      = (const float*)d_in[3];
  const float* D      = (const float*)d_in[4];
  const float* log_dt = (const float*)d_in[5];
  const float* W      = (const float*)d_in[6];
  const float* b_out  = (const float*)d_in[7];
  float* out = (float*)d_out;
  float* fs  = out + (long)MROWS * D_MODEL;  // final_state (8x32) after y

  char* ws = (char*)d_ws;
  float* A_bar = (float*)(ws + 0);                    // 4 KB
  bf16*  Bhi   = (bf16*)(ws + (4L << 10));            // 32 KB
  bf16*  Blo   = (bf16*)(ws + (36L << 10));           // 32 KB
  bf16*  CW    = (bf16*)(ws + (68L << 10));           // 32 KB
  bf16*  WD    = (bf16*)(ws + (100L << 10));          // 512 KB
  bf16*  Sb    = (bf16*)(ws + (612L << 10));          // 2 MB
  float* uB    = (float*)(ws + (2660L << 10));        // 4 MB
  bf16*  xb    = (bf16*)(ws + (6756L << 10));         // 32 MB   (total ~38.6 MB)

  k_precompute<<<dim3(1), dim3(256), 0, stream>>>(A, B, log_dt, A_bar, Bhi, Blo);
  k_weights<<<dim3(128), dim3(256), 0, stream>>>(C, D, W, CW, WD);
  k_ub<<<dim3(MROWS / 128), dim3(256), 0, stream>>>(x, Bhi, Blo, uB, xb);
  k_scan<<<dim3(BATCH * NCHUNK / 2), dim3(64), 0, stream>>>(uB, A_bar, Sb, fs);
  k_out<<<dim3((MROWS / 128) * (D_MODEL / 128)), dim3(256), 0, stream>>>(xb, WD, Sb, CW, b_out, out);
}